// Round 11
// baseline (756.027 us; speedup 1.0000x reference)
//
#include <hip/hip_runtime.h>
#include <stdint.h>

#define Bn 4
#define Sn 2048
#define Hn 1024
#define Ln 4
#define Mn (Bn*Sn)          // 8192 rows
#define CHUNK 32
#define NCH (Sn/CHUNK)      // 64

typedef __bf16 bf16x8 __attribute__((ext_vector_type(8)));
typedef float  f32x4  __attribute__((ext_vector_type(4)));
typedef uint32_t u32;

__device__ __forceinline__ unsigned short f2bf(float f) {
  uint32_t u = __float_as_uint(f);
  uint32_t r = (u + 0x7FFFu + ((u >> 16) & 1u)) >> 16;
  return (unsigned short)r;
}
__device__ __forceinline__ float bf2f(unsigned short u) {
  return __uint_as_float(((uint32_t)u) << 16);
}

__device__ __forceinline__ void gload_lds16(const void* g, void* l) {
  __builtin_amdgcn_global_load_lds((const __attribute__((address_space(1))) void*)g,
                                   (__attribute__((address_space(3))) void*)l, 16, 0, 0);
}

// ---------------- single fused cast f32 -> bf16 (round-11: 6 dispatches -> 1) ----------------
// segments (float4 units): fwd_Wz 1M | bwd_Wz 1M | fwd_Wh 1M | bwd_Wh 1M | fusW 512K | x 2M
__global__ __launch_bounds__(256) void cast_all(
    const float* __restrict__ s0, const float* __restrict__ s1,
    const float* __restrict__ s2, const float* __restrict__ s3,
    const float* __restrict__ s4, const float* __restrict__ s5,
    unsigned short* __restrict__ d0, unsigned short* __restrict__ d1,
    unsigned short* __restrict__ d2, unsigned short* __restrict__ d3,
    unsigned short* __restrict__ d4, unsigned short* __restrict__ d5) {
  long i = (long)blockIdx.x * 256 + threadIdx.x;   // grid sized exactly: 6815744 / 256
  const float* s; unsigned short* d; long off;
  if      (i < 1048576) { s = s0; d = d0; off = i; }
  else if (i < 2097152) { s = s1; d = d1; off = i - 1048576; }
  else if (i < 3145728) { s = s2; d = d2; off = i - 2097152; }
  else if (i < 4194304) { s = s3; d = d3; off = i - 3145728; }
  else if (i < 4718592) { s = s4; d = d4; off = i - 4194304; }
  else                  { s = s5; d = d5; off = i - 4718592; }
  float4 v = reinterpret_cast<const float4*>(s)[off];
  ushort4 o;
  o.x = f2bf(v.x); o.y = f2bf(v.y); o.z = f2bf(v.z); o.w = f2bf(v.w);
  reinterpret_cast<ushort4*>(d)[off] = o;
}

// ---------------- GEMM: out[M,N] = act[M,K](bf16) @ W[N,K]^T (bf16) + bias ----------------
// UNCHANGED from round-8/9/10 (measured: layer ~42.5 us / 810 TF, fusion ~43 us —
// at the m248 reference level for this K=1024 shape; schedule frozen).

#define DSR(d, b, imm) \
  asm volatile("ds_read_b128 %0, %1 offset:%c2" : "=&v"(d) : "v"(b), "i"(imm))

#define VMW(n) do { \
    asm volatile("s_waitcnt vmcnt(" #n ")"); \
    __builtin_amdgcn_sched_barrier(0); \
  } while (0)

#define LGKM(n) do { \
    asm volatile("s_waitcnt lgkmcnt(" #n ")"); \
    __builtin_amdgcn_sched_barrier(0); \
  } while (0)

#define DSR4(ARR, base, off) do { \
    DSR(ARR[0], base, (off)); \
    DSR(ARR[1], base, (off) + 1024); \
    DSR(ARR[2], base, (off) + 2048); \
    DSR(ARR[3], base, (off) + 3072); \
  } while (0)

#define CL(ARR, BARR, MB) do { \
    __builtin_amdgcn_s_setprio(1); \
    _Pragma("unroll") \
    for (int _m = 0; _m < 4; ++_m) { \
      _Pragma("unroll") \
      for (int _n = 0; _n < 4; ++_n) \
        acc[(MB) + _m][_n] = __builtin_amdgcn_mfma_f32_16x16x32_bf16( \
            ARR[_m], BARR[_n], acc[(MB) + _m][_n], 0, 0, 0); \
    } \
    __builtin_amdgcn_s_setprio(0); \
  } while (0)

#define BODY(buf) do { \
    if constexpr (MF == 8) { \
      DSR4(aA, baseA, ((buf) * 2 + 0) * RGA); \
      DSR4(b0, baseB, ((buf) * 2 + 0) * 16384); \
      DSR4(aB, baseA, ((buf) * 2 + 0) * RGA + 4096); \
      LGKM(4); \
      CL(aA, b0, 0); \
      DSR4(b1, baseB, ((buf) * 2 + 1) * 16384); \
      LGKM(4); \
      CL(aB, b0, 4); \
      DSR4(aA, baseA, ((buf) * 2 + 1) * RGA); \
      LGKM(4); \
      DSR4(aB, baseA, ((buf) * 2 + 1) * RGA + 4096); \
      LGKM(4); \
      CL(aA, b1, 0); \
      LGKM(0); \
      CL(aB, b1, 4); \
    } else { \
      DSR4(aA, baseA, ((buf) * 2 + 0) * RGA); \
      DSR4(b0, baseB, ((buf) * 2 + 0) * 16384); \
      DSR4(aB, baseA, ((buf) * 2 + 1) * RGA); \
      LGKM(4); \
      CL(aA, b0, 0); \
      DSR4(b1, baseB, ((buf) * 2 + 1) * 16384); \
      LGKM(0); \
      CL(aB, b1, 0); \
    } \
  } while (0)

template<int MF>
__global__ __launch_bounds__(512, 2) void gemm_t(
    const unsigned short* __restrict__ act,  // M x K
    const unsigned short* __restrict__ Wlo,  // rows [0, Nsplit)
    const unsigned short* __restrict__ Whi,  // rows [Nsplit, N)
    const float* __restrict__ bias0, const float* __restrict__ bias1,
    int Nsplit, float* __restrict__ out, unsigned short* __restrict__ outbf,
    int Ndim, int K) {
  constexpr int BMR = MF * 32;            // 256 or 128 rows
  constexpr int RGA = BMR * 64;           // A (buf,kh)-region bytes: 16384 or 8192
  __shared__ unsigned char smA[4 * RGA];
  __shared__ unsigned char smB[65536];
  const int tid  = threadIdx.x;
  const int lane = tid & 63;
  const int w    = tid >> 6;           // 0..7
  const int waveM = w >> 2;            // 0..1
  const int waveN = w & 3;             // 0..3  (64 cols each)
  const int bm = blockIdx.x, bn = blockIdx.y;

  const unsigned short* Wp; int nbase;
  if (bn * 256 < Nsplit) { Wp = Wlo; nbase = bn * 256; }
  else                   { Wp = Whi; nbase = bn * 256 - Nsplit; }

  const int swz  = (((lane >> 4) ^ ((lane >> 1) & 3)) << 4);
  const int aoff = (waveM * (MF * 16) + (lane & 15)) * 64 + swz;
  const int boff = (waveN * 64 + (lane & 15)) * 64 + swz;

  const u32 baseA = (u32)(size_t)(void*)&smA[0] + (u32)aoff;
  const u32 baseB = (u32)(size_t)(void*)&smB[0] + (u32)boff;

  const int srow = tid >> 2;
  const int slog = (tid & 3) ^ ((srow >> 1) & 3);
  const unsigned short* aS0 = act + (size_t)(bm * BMR + srow) * K + slog * 8;
  const unsigned short* aS1 = aS0 + (size_t)128 * K;   // used only when MF==8
  const unsigned short* bS0 = Wp  + (size_t)(nbase + srow) * K + slog * 8;
  const unsigned short* bS1 = bS0 + (size_t)128 * K;
  const int wB = w * 1024;

  f32x4 acc[MF][4];
#pragma unroll
  for (int m = 0; m < MF; ++m)
#pragma unroll
    for (int n = 0; n < 4; ++n) acc[m][n] = (f32x4)0.0f;

  bf16x8 aA[4], aB[4], b0[4], b1[4];

  auto STG4 = [&](int t, int buf) {
#pragma unroll
    for (int kh = 0; kh < 2; ++kh) {
      unsigned char* ra = smA + (buf * 2 + kh) * RGA;
      gload_lds16(aS0 + (size_t)t * 64 + kh * 32, ra + wB);
      if constexpr (MF == 8)
        gload_lds16(aS1 + (size_t)t * 64 + kh * 32, ra + 8192 + wB);
      unsigned char* rb = smB + (buf * 2 + kh) * 16384;
      gload_lds16(bS0 + (size_t)t * 64 + kh * 32, rb + wB);
      gload_lds16(bS1 + (size_t)t * 64 + kh * 32, rb + 8192 + wB);
    }
  };

  const int nkt   = K >> 6;   // K-tiles (even)
  const int niter = nkt >> 1;

  STG4(0, 0);
  VMW(0);
  __builtin_amdgcn_s_barrier();

  for (int j = 0; j < niter - 1; ++j) {
    STG4(2 * j + 1, 1); BODY(0); VMW(0); __builtin_amdgcn_s_barrier();
    STG4(2 * j + 2, 0); BODY(1); VMW(0); __builtin_amdgcn_s_barrier();
  }
  STG4(nkt - 1, 1); BODY(0); VMW(0); __builtin_amdgcn_s_barrier();
  BODY(1);

  const int colBase = bn * 256 + waveN * 64;
  const int rowBase = bm * BMR + waveM * (MF * 16);
#pragma unroll
  for (int m = 0; m < MF; ++m) {
#pragma unroll
    for (int n = 0; n < 4; ++n) {
      int col = colBase + n * 16 + (lane & 15);
      float bv = (col < Nsplit) ? bias0[col] : bias1[col - Nsplit];
      if (outbf) {
#pragma unroll
        for (int r = 0; r < 4; ++r) {
          int row = rowBase + m * 16 + (lane >> 4) * 4 + r;
          outbf[(size_t)row * Ndim + col] = f2bf(acc[m][n][r] + bv);
        }
      } else {
#pragma unroll
        for (int r = 0; r < 4; ++r) {
          int row = rowBase + m * 16 + (lane >> 4) * 4 + r;
          out[(size_t)row * Ndim + col] = acc[m][n][r] + bv;
        }
      }
    }
  }
}

// ---------------- pointwise helpers ----------------
__device__ __forceinline__ void gate_ab(float zp, float hp, float& a, float& bv) {
  float z  = 1.0f / (1.0f + __expf(-zp));
  float e  = __expf(-2.0f * fabsf(hp));
  float th = (1.0f - e) / (1.0f + e);
  th = (hp >= 0.0f) ? th : -th;
  a  = fminf(fmaxf(1.0f - z, 1e-8f), 1.0f - 1e-8f);
  bv = z * th;
}

// ---------------- scan pass 1 (round-11: u32 loads, 2 h per thread) ----------------
// grid = Bn * NCH * 2 blocks of 256; thread owns h0 = ht*512 + tid*2 and h0+1.
// Per-h math identical to round 10 -> bit-identical Ac/Bc.
__global__ __launch_bounds__(256) void scan_p1(const unsigned short* __restrict__ pre,
                                               float* __restrict__ Ac, float* __restrict__ Bc,
                                               int dir) {
  int tid = threadIdx.x;
  int bid = blockIdx.x;
  int ht = bid & 1;
  int c  = (bid >> 1) & (NCH - 1);
  int b  = bid >> 7;
  int h0 = ht * 512 + tid * 2;
  float A0 = 1.0f, B0 = 0.0f, A1 = 1.0f, B1 = 0.0f;
  for (int j = 0; j < CHUNK; ++j) {
    int t = c * CHUNK + j;
    int s = dir ? (Sn - 1 - t) : t;
    const unsigned short* p = pre + (size_t)(b * Sn + s) * 2048;
    u32 zp = *reinterpret_cast<const u32*>(p + h0);
    u32 hp = *reinterpret_cast<const u32*>(p + 1024 + h0);
    float a, bv;
    gate_ab(bf2f((unsigned short)(zp & 0xffffu)), bf2f((unsigned short)(hp & 0xffffu)), a, bv);
    A0 = a * A0; B0 = a * B0 + bv;
    gate_ab(bf2f((unsigned short)(zp >> 16)), bf2f((unsigned short)(hp >> 16)), a, bv);
    A1 = a * A1; B1 = a * B1 + bv;
  }
  size_t idx = (size_t)(b * NCH + c) * Hn + h0;
  *reinterpret_cast<float2*>(&Ac[idx]) = make_float2(A0, A1);
  *reinterpret_cast<float2*>(&Bc[idx]) = make_float2(B0, B1);
}

// ---------------- scan pass 3 + prefix + LayerNorm (round-11) ----------------
// Changes vs round 10:
//  * scan_mid folded in: block (b,c) folds Ac/Bc[0..c-1] itself (same fold order
//    as mid -> bit-identical hprev), software-pipelined 8-wide so L2/L3 latency
//    is paid once per 8 chunks. Deletes the mid dispatch and the pref buffer.
//  * 512 threads, each owning 2 adjacent h: scan-phase pre loads become u32
//    (4B/lane, was 2B scalar); LDS writes become u32. 64KB LDS + 512 thr -> can
//    co-reside 2 blocks/CU.
//  * LN phase: 8 waves x 4 rows (identical per-row math to round 10).
__global__ __launch_bounds__(512) void scan_p3_ln(
    const unsigned short* __restrict__ pre,
    const float* __restrict__ Ac, const float* __restrict__ Bc,
    const unsigned short* __restrict__ resid,   // bf16; may be null; may alias out_bf
    const float* __restrict__ gamma, const float* __restrict__ beta,
    unsigned short* __restrict__ out_bf,
    int bf_stride, int bf_off, int dir) {
  __shared__ unsigned short hsl[CHUNK][Hn];   // 64 KB
  const int tid = threadIdx.x;
  const int h0  = tid * 2;
  const int c   = blockIdx.x & (NCH - 1);
  const int b   = blockIdx.x >> 6;            // NCH = 64

  // ---- prefix fold over chunks 0..c-1 (replaces scan_mid; same fold order) ----
  float r0 = 0.0f, r1 = 0.0f;
  {
    int cc = 0;
    for (; cc + 8 <= c; cc += 8) {
      float2 A2[8], B2[8];
#pragma unroll
      for (int q = 0; q < 8; ++q) {
        size_t idx = (size_t)(b * NCH + cc + q) * Hn + h0;
        A2[q] = *reinterpret_cast<const float2*>(&Ac[idx]);
        B2[q] = *reinterpret_cast<const float2*>(&Bc[idx]);
      }
#pragma unroll
      for (int q = 0; q < 8; ++q) {
        r0 = A2[q].x * r0 + B2[q].x;
        r1 = A2[q].y * r1 + B2[q].y;
      }
    }
    for (; cc < c; ++cc) {
      size_t idx = (size_t)(b * NCH + cc) * Hn + h0;
      float2 A2 = *reinterpret_cast<const float2*>(&Ac[idx]);
      float2 B2 = *reinterpret_cast<const float2*>(&Bc[idx]);
      r0 = A2.x * r0 + B2.x;
      r1 = A2.y * r1 + B2.y;
    }
  }

  // ---- scan phase (no barriers; u32 loads, 2 h per thread) ----
  for (int j = 0; j < CHUNK; ++j) {
    int t = c * CHUNK + j;
    int s = dir ? (Sn - 1 - t) : t;
    const unsigned short* p = pre + (size_t)(b * Sn + s) * 2048;
    u32 zp = *reinterpret_cast<const u32*>(p + h0);
    u32 hp = *reinterpret_cast<const u32*>(p + 1024 + h0);
    float a, bv;
    gate_ab(bf2f((unsigned short)(zp & 0xffffu)), bf2f((unsigned short)(hp & 0xffffu)), a, bv);
    r0 = a * r0 + bv;
    gate_ab(bf2f((unsigned short)(zp >> 16)), bf2f((unsigned short)(hp >> 16)), a, bv);
    r1 = a * r1 + bv;
    *reinterpret_cast<u32*>(&hsl[j][h0]) = (u32)f2bf(r0) | ((u32)f2bf(r1) << 16);
  }
  __syncthreads();

  // ---- LN phase: wave wv handles rows wv*4 .. wv*4+3 ----
  const int lane = tid & 63;
  const int wv   = tid >> 6;                  // 0..7
  // per-lane gamma/beta: h in {lane*8..+7} u {512+lane*8..+7}
  float gm[16], bt[16];
  {
    const float4* gp = reinterpret_cast<const float4*>(gamma);
    const float4* bp = reinterpret_cast<const float4*>(beta);
#pragma unroll
    for (int half = 0; half < 2; ++half) {
      int base = half * 128 + lane * 2;
#pragma unroll
      for (int i = 0; i < 2; ++i) {
        float4 g4 = gp[base + i], b4 = bp[base + i];
        int o = half * 8 + i * 4;
        gm[o+0] = g4.x; gm[o+1] = g4.y; gm[o+2] = g4.z; gm[o+3] = g4.w;
        bt[o+0] = b4.x; bt[o+1] = b4.y; bt[o+2] = b4.z; bt[o+3] = b4.w;
      }
    }
  }

  for (int rr = 0; rr < 4; ++rr) {
    const int j = wv * 4 + rr;
    const int t = c * CHUNK + j;
    const int s = dir ? (Sn - 1 - t) : t;
    const size_t row = (size_t)(b * Sn + s);

    const uint4* rp = reinterpret_cast<const uint4*>(&hsl[j][0]);
    uint4 q0 = rp[lane], q1 = rp[64 + lane];
    uint32_t uw[8] = {q0.x, q0.y, q0.z, q0.w, q1.x, q1.y, q1.z, q1.w};
    float v[16];
#pragma unroll
    for (int k = 0; k < 8; ++k) {
      v[2*k]   = bf2f((unsigned short)(uw[k] & 0xffffu));
      v[2*k+1] = bf2f((unsigned short)(uw[k] >> 16));
    }
    if (resid) {
      const uint4* rf = reinterpret_cast<const uint4*>(resid + row * Hn);
      uint4 r0v = rf[lane], r1v = rf[64 + lane];
      uint32_t rw[8] = {r0v.x, r0v.y, r0v.z, r0v.w, r1v.x, r1v.y, r1v.z, r1v.w};
#pragma unroll
      for (int k = 0; k < 8; ++k) {
        v[2*k]   += bf2f((unsigned short)(rw[k] & 0xffffu));
        v[2*k+1] += bf2f((unsigned short)(rw[k] >> 16));
      }
    }
    float s1 = 0.0f, s2 = 0.0f;
#pragma unroll
    for (int m = 0; m < 16; ++m) { s1 += v[m]; s2 += v[m] * v[m]; }
#pragma unroll
    for (int off = 1; off < 64; off <<= 1) {
      s1 += __shfl_xor(s1, off);
      s2 += __shfl_xor(s2, off);
    }
    float mu  = s1 * (1.0f / Hn);
    float var = s2 * (1.0f / Hn) - mu * mu;
    float rs  = rsqrtf(var + 1e-5f);

    float o[16];
#pragma unroll
    for (int m = 0; m < 16; ++m) o[m] = (v[m] - mu) * rs * gm[m] + bt[m];

    uint4* ob = reinterpret_cast<uint4*>(out_bf + row * bf_stride + bf_off);
    uint4 w0, w1;
    w0.x = f2bf(o[0])  | ((u32)f2bf(o[1])  << 16);
    w0.y = f2bf(o[2])  | ((u32)f2bf(o[3])  << 16);
    w0.z = f2bf(o[4])  | ((u32)f2bf(o[5])  << 16);
    w0.w = f2bf(o[6])  | ((u32)f2bf(o[7])  << 16);
    w1.x = f2bf(o[8])  | ((u32)f2bf(o[9])  << 16);
    w1.y = f2bf(o[10]) | ((u32)f2bf(o[11]) << 16);
    w1.z = f2bf(o[12]) | ((u32)f2bf(o[13]) << 16);
    w1.w = f2bf(o[14]) | ((u32)f2bf(o[15]) << 16);
    ob[lane]      = w0;
    ob[64 + lane] = w1;
  }
}

// ---------------- launcher ----------------
extern "C" void kernel_launch(void* const* d_in, const int* in_sizes, int n_in,
                              void* d_out, int out_size, void* d_ws, size_t ws_size,
                              hipStream_t stream) {
  const float* x        = (const float*)d_in[0];
  const float* fwd_Wz   = (const float*)d_in[1];
  const float* fwd_bz   = (const float*)d_in[2];
  const float* fwd_Wh   = (const float*)d_in[3];
  const float* fwd_bh   = (const float*)d_in[4];
  const float* bwd_Wz   = (const float*)d_in[5];
  const float* bwd_bz   = (const float*)d_in[6];
  const float* bwd_Wh   = (const float*)d_in[7];
  const float* bwd_bh   = (const float*)d_in[8];
  const float* fusion_W = (const float*)d_in[9];
  const float* fusion_b = (const float*)d_in[10];
  const float* gamma    = (const float*)d_in[11];
  const float* beta     = (const float*)d_in[12];
  float* out = (float*)d_out;

  // workspace layout (pre bf16; actf/hs/pref slots retained but unused)
  unsigned short* WzA    = (unsigned short*)d_ws;              // 2*4*1024*1024
  unsigned short* WhA    = WzA + 8ULL * 1024 * 1024;           // 2*4*1024*1024
  unsigned short* fusWbf = WhA + 8ULL * 1024 * 1024;           // 1024*2048
  unsigned short* xbf    = fusWbf + 2ULL * 1024 * 1024;        // 8192*1024
  unsigned short* actbf  = xbf + 8ULL * 1024 * 1024;           // 8192*1024 (GEMM in + resid)
  unsigned short* combbf = actbf + 8ULL * 1024 * 1024;         // 8192*2048
  float* actf = (float*)(combbf + 16ULL * 1024 * 1024);        // unused (layout keep)
  float* pre  = actf + 8ULL * 1024 * 1024;                     // 8192*2048 (bf16 uses half)
  float* hs   = pre + 16ULL * 1024 * 1024;                     // unused (layout keep)
  float* Ac   = hs + 8ULL * 1024 * 1024;                       // 4*NCH*1024
  float* Bc   = Ac + (size_t)Bn * NCH * Hn;
  float* pref = Bc + (size_t)Bn * NCH * Hn;                    // unused (layout keep)
  size_t need = (size_t)((char*)(pref + (size_t)Bn * NCH * Hn) - (char*)d_ws);
  if (ws_size < need) return;
  unsigned short* prebf = (unsigned short*)pre;

  // one fused cast dispatch (was 6)
  cast_all<<<26624, 256, 0, stream>>>(
      fwd_Wz, bwd_Wz, fwd_Wh, bwd_Wh, fusion_W, x,
      WzA, WzA + 4ULL * 1024 * 1024, WhA, WhA + 4ULL * 1024 * 1024, fusWbf, xbf);

  for (int d = 0; d < 2; ++d) {
    const float* bz = d ? bwd_bz : fwd_bz;
    const float* bh = d ? bwd_bh : fwd_bh;
    for (int l = 0; l < Ln; ++l) {
      const unsigned short* a_in = (l == 0) ? xbf : actbf;
      const unsigned short* Wlo = WzA + (size_t)(d * 4 + l) * 1024 * 1024;
      const unsigned short* Whi = WhA + (size_t)(d * 4 + l) * 1024 * 1024;
      gemm_t<8><<<dim3(Mn / 256, 2048 / 256), 512, 0, stream>>>(
          a_in, Wlo, Whi, bz + l * 1024, bh + l * 1024, 1024,
          nullptr, prebf, 2048, 1024);
      scan_p1<<<Bn * NCH * 2, 256, 0, stream>>>(prebf, Ac, Bc, d);
      if (l < Ln - 1)
        scan_p3_ln<<<Bn * NCH, 512, 0, stream>>>(
            prebf, Ac, Bc, (l == 0) ? nullptr : actbf, gamma, beta,
            actbf, 1024, 0, d);
      else
        scan_p3_ln<<<Bn * NCH, 512, 0, stream>>>(
            prebf, Ac, Bc, actbf, gamma, beta,
            combbf, 2048, d * 1024, d);
    }
  }
  // fusion: out = comb(bf16) @ fusion_W^T + fusion_b (f32 output, BM=128 -> 256 blocks)
  gemm_t<4><<<dim3(Mn / 128, 1024 / 256), 512, 0, stream>>>(
      combbf, fusWbf, fusWbf, fusion_b, fusion_b, 1 << 30, out, nullptr, 1024, 2048);
}

// Round 12
// 680.987 us; speedup vs baseline: 1.1102x; 1.1102x over previous
//
#include <hip/hip_runtime.h>
#include <stdint.h>

#define Bn 4
#define Sn 2048
#define Hn 1024
#define Ln 4
#define Mn (Bn*Sn)          // 8192 rows
#define CHUNK 32
#define NCH (Sn/CHUNK)      // 64

typedef __bf16 bf16x8 __attribute__((ext_vector_type(8)));
typedef float  f32x4  __attribute__((ext_vector_type(4)));
typedef uint32_t u32;

__device__ __forceinline__ unsigned short f2bf(float f) {
  uint32_t u = __float_as_uint(f);
  uint32_t r = (u + 0x7FFFu + ((u >> 16) & 1u)) >> 16;
  return (unsigned short)r;
}
__device__ __forceinline__ float bf2f(unsigned short u) {
  return __uint_as_float(((uint32_t)u) << 16);
}

__device__ __forceinline__ void gload_lds16(const void* g, void* l) {
  __builtin_amdgcn_global_load_lds((const __attribute__((address_space(1))) void*)g,
                                   (__attribute__((address_space(3))) void*)l, 16, 0, 0);
}

// ---------------- single fused cast f32 -> bf16 (6 dispatches -> 1) ----------------
__global__ __launch_bounds__(256) void cast_all(
    const float* __restrict__ s0, const float* __restrict__ s1,
    const float* __restrict__ s2, const float* __restrict__ s3,
    const float* __restrict__ s4, const float* __restrict__ s5,
    unsigned short* __restrict__ d0, unsigned short* __restrict__ d1,
    unsigned short* __restrict__ d2, unsigned short* __restrict__ d3,
    unsigned short* __restrict__ d4, unsigned short* __restrict__ d5) {
  long i = (long)blockIdx.x * 256 + threadIdx.x;   // grid = 6815744 / 256
  const float* s; unsigned short* d; long off;
  if      (i < 1048576) { s = s0; d = d0; off = i; }
  else if (i < 2097152) { s = s1; d = d1; off = i - 1048576; }
  else if (i < 3145728) { s = s2; d = d2; off = i - 2097152; }
  else if (i < 4194304) { s = s3; d = d3; off = i - 3145728; }
  else if (i < 4718592) { s = s4; d = d4; off = i - 4194304; }
  else                  { s = s5; d = d5; off = i - 4718592; }
  float4 v = reinterpret_cast<const float4*>(s)[off];
  ushort4 o;
  o.x = f2bf(v.x); o.y = f2bf(v.y); o.z = f2bf(v.z); o.w = f2bf(v.w);
  reinterpret_cast<ushort4*>(d)[off] = o;
}

// ---------------- GEMM: out[M,N] = act[M,K](bf16) @ W[N,K]^T (bf16) + bias ----------------
// UNCHANGED (frozen since round 8: layer ~42.5 us / 810 TF, fusion ~43 us).

#define DSR(d, b, imm) \
  asm volatile("ds_read_b128 %0, %1 offset:%c2" : "=&v"(d) : "v"(b), "i"(imm))

#define VMW(n) do { \
    asm volatile("s_waitcnt vmcnt(" #n ")"); \
    __builtin_amdgcn_sched_barrier(0); \
  } while (0)

#define LGKM(n) do { \
    asm volatile("s_waitcnt lgkmcnt(" #n ")"); \
    __builtin_amdgcn_sched_barrier(0); \
  } while (0)

#define DSR4(ARR, base, off) do { \
    DSR(ARR[0], base, (off)); \
    DSR(ARR[1], base, (off) + 1024); \
    DSR(ARR[2], base, (off) + 2048); \
    DSR(ARR[3], base, (off) + 3072); \
  } while (0)

#define CL(ARR, BARR, MB) do { \
    __builtin_amdgcn_s_setprio(1); \
    _Pragma("unroll") \
    for (int _m = 0; _m < 4; ++_m) { \
      _Pragma("unroll") \
      for (int _n = 0; _n < 4; ++_n) \
        acc[(MB) + _m][_n] = __builtin_amdgcn_mfma_f32_16x16x32_bf16( \
            ARR[_m], BARR[_n], acc[(MB) + _m][_n], 0, 0, 0); \
    } \
    __builtin_amdgcn_s_setprio(0); \
  } while (0)

#define BODY(buf) do { \
    if constexpr (MF == 8) { \
      DSR4(aA, baseA, ((buf) * 2 + 0) * RGA); \
      DSR4(b0, baseB, ((buf) * 2 + 0) * 16384); \
      DSR4(aB, baseA, ((buf) * 2 + 0) * RGA + 4096); \
      LGKM(4); \
      CL(aA, b0, 0); \
      DSR4(b1, baseB, ((buf) * 2 + 1) * 16384); \
      LGKM(4); \
      CL(aB, b0, 4); \
      DSR4(aA, baseA, ((buf) * 2 + 1) * RGA); \
      LGKM(4); \
      DSR4(aB, baseA, ((buf) * 2 + 1) * RGA + 4096); \
      LGKM(4); \
      CL(aA, b1, 0); \
      LGKM(0); \
      CL(aB, b1, 4); \
    } else { \
      DSR4(aA, baseA, ((buf) * 2 + 0) * RGA); \
      DSR4(b0, baseB, ((buf) * 2 + 0) * 16384); \
      DSR4(aB, baseA, ((buf) * 2 + 1) * RGA); \
      LGKM(4); \
      CL(aA, b0, 0); \
      DSR4(b1, baseB, ((buf) * 2 + 1) * 16384); \
      LGKM(0); \
      CL(aB, b1, 0); \
    } \
  } while (0)

template<int MF>
__global__ __launch_bounds__(512, 2) void gemm_t(
    const unsigned short* __restrict__ act,  // M x K
    const unsigned short* __restrict__ Wlo,  // rows [0, Nsplit)
    const unsigned short* __restrict__ Whi,  // rows [Nsplit, N)
    const float* __restrict__ bias0, const float* __restrict__ bias1,
    int Nsplit, float* __restrict__ out, unsigned short* __restrict__ outbf,
    int Ndim, int K) {
  constexpr int BMR = MF * 32;            // 256 or 128 rows
  constexpr int RGA = BMR * 64;           // A (buf,kh)-region bytes: 16384 or 8192
  __shared__ unsigned char smA[4 * RGA];
  __shared__ unsigned char smB[65536];
  const int tid  = threadIdx.x;
  const int lane = tid & 63;
  const int w    = tid >> 6;           // 0..7
  const int waveM = w >> 2;            // 0..1
  const int waveN = w & 3;             // 0..3  (64 cols each)
  const int bm = blockIdx.x, bn = blockIdx.y;

  const unsigned short* Wp; int nbase;
  if (bn * 256 < Nsplit) { Wp = Wlo; nbase = bn * 256; }
  else                   { Wp = Whi; nbase = bn * 256 - Nsplit; }

  const int swz  = (((lane >> 4) ^ ((lane >> 1) & 3)) << 4);
  const int aoff = (waveM * (MF * 16) + (lane & 15)) * 64 + swz;
  const int boff = (waveN * 64 + (lane & 15)) * 64 + swz;

  const u32 baseA = (u32)(size_t)(void*)&smA[0] + (u32)aoff;
  const u32 baseB = (u32)(size_t)(void*)&smB[0] + (u32)boff;

  const int srow = tid >> 2;
  const int slog = (tid & 3) ^ ((srow >> 1) & 3);
  const unsigned short* aS0 = act + (size_t)(bm * BMR + srow) * K + slog * 8;
  const unsigned short* aS1 = aS0 + (size_t)128 * K;   // used only when MF==8
  const unsigned short* bS0 = Wp  + (size_t)(nbase + srow) * K + slog * 8;
  const unsigned short* bS1 = bS0 + (size_t)128 * K;
  const int wB = w * 1024;

  f32x4 acc[MF][4];
#pragma unroll
  for (int m = 0; m < MF; ++m)
#pragma unroll
    for (int n = 0; n < 4; ++n) acc[m][n] = (f32x4)0.0f;

  bf16x8 aA[4], aB[4], b0[4], b1[4];

  auto STG4 = [&](int t, int buf) {
#pragma unroll
    for (int kh = 0; kh < 2; ++kh) {
      unsigned char* ra = smA + (buf * 2 + kh) * RGA;
      gload_lds16(aS0 + (size_t)t * 64 + kh * 32, ra + wB);
      if constexpr (MF == 8)
        gload_lds16(aS1 + (size_t)t * 64 + kh * 32, ra + 8192 + wB);
      unsigned char* rb = smB + (buf * 2 + kh) * 16384;
      gload_lds16(bS0 + (size_t)t * 64 + kh * 32, rb + wB);
      gload_lds16(bS1 + (size_t)t * 64 + kh * 32, rb + 8192 + wB);
    }
  };

  const int nkt   = K >> 6;   // K-tiles (even)
  const int niter = nkt >> 1;

  STG4(0, 0);
  VMW(0);
  __builtin_amdgcn_s_barrier();

  for (int j = 0; j < niter - 1; ++j) {
    STG4(2 * j + 1, 1); BODY(0); VMW(0); __builtin_amdgcn_s_barrier();
    STG4(2 * j + 2, 0); BODY(1); VMW(0); __builtin_amdgcn_s_barrier();
  }
  STG4(nkt - 1, 1); BODY(0); VMW(0); __builtin_amdgcn_s_barrier();
  BODY(1);

  const int colBase = bn * 256 + waveN * 64;
  const int rowBase = bm * BMR + waveM * (MF * 16);
#pragma unroll
  for (int m = 0; m < MF; ++m) {
#pragma unroll
    for (int n = 0; n < 4; ++n) {
      int col = colBase + n * 16 + (lane & 15);
      float bv = (col < Nsplit) ? bias0[col] : bias1[col - Nsplit];
      if (outbf) {
#pragma unroll
        for (int r = 0; r < 4; ++r) {
          int row = rowBase + m * 16 + (lane >> 4) * 4 + r;
          outbf[(size_t)row * Ndim + col] = f2bf(acc[m][n][r] + bv);
        }
      } else {
#pragma unroll
        for (int r = 0; r < 4; ++r) {
          int row = rowBase + m * 16 + (lane >> 4) * 4 + r;
          out[(size_t)row * Ndim + col] = acc[m][n][r] + bv;
        }
      }
    }
  }
}

// ---------------- pointwise helpers ----------------
__device__ __forceinline__ void gate_ab(float zp, float hp, float& a, float& bv) {
  float z  = 1.0f / (1.0f + __expf(-zp));
  float e  = __expf(-2.0f * fabsf(hp));
  float th = (1.0f - e) / (1.0f + e);
  th = (hp >= 0.0f) ? th : -th;
  a  = fminf(fmaxf(1.0f - z, 1e-8f), 1.0f - 1e-8f);
  bv = z * th;
}

// ---------------- scan pass 1 (round-10 exact: 1 h/thread, 16 waves/CU) ----------------
__global__ __launch_bounds__(256) void scan_p1(const unsigned short* __restrict__ pre,
                                               float* __restrict__ Ac, float* __restrict__ Bc,
                                               int dir) {
  int tid = threadIdx.x;
  int bid = blockIdx.x;
  int ht = bid & 3;
  int c  = (bid >> 2) & (NCH - 1);
  int b  = bid >> 8;
  int h  = ht * 256 + tid;
  float Aa = 1.0f, Bb = 0.0f;
  for (int j = 0; j < CHUNK; ++j) {
    int t = c * CHUNK + j;
    int s = dir ? (Sn - 1 - t) : t;
    const unsigned short* p = pre + (size_t)(b * Sn + s) * 2048;
    float a, bv;
    gate_ab(bf2f(p[h]), bf2f(p[1024 + h]), a, bv);
    Aa = a * Aa;
    Bb = a * Bb + bv;
  }
  Ac[(size_t)(b * NCH + c) * Hn + h] = Aa;
  Bc[(size_t)(b * NCH + c) * Hn + h] = Bb;
}

// ---------------- scan pass 3 + prefix + LayerNorm (round-12) ----------------
// Round-10 body (1024 threads, 16 waves/CU — round-11's 512-thread variant halved
// scan-phase TLP and regressed) + the prefix fold replacing scan_mid (same fold
// order -> bit-identical hprev; 8-wide software pipeline; scalar f32 loads, fully
// coalesced). resid bf16, may alias out_bf (per-thread read-before-write).
__global__ __launch_bounds__(1024) void scan_p3_ln(
    const unsigned short* __restrict__ pre,
    const float* __restrict__ Ac, const float* __restrict__ Bc,
    const unsigned short* __restrict__ resid,
    const float* __restrict__ gamma, const float* __restrict__ beta,
    unsigned short* __restrict__ out_bf,
    int bf_stride, int bf_off, int dir) {
  __shared__ unsigned short hsl[CHUNK][Hn];   // 64 KB
  const int h = threadIdx.x;
  const int c = blockIdx.x & (NCH - 1);
  const int b = blockIdx.x >> 6;              // NCH = 64

  // ---- prefix fold over chunks 0..c-1 (replaces scan_mid; same fold order) ----
  float hprev = 0.0f;
  {
    int cc = 0;
    for (; cc + 8 <= c; cc += 8) {
      float Af[8], Bf[8];
#pragma unroll
      for (int q = 0; q < 8; ++q) {
        size_t idx = (size_t)(b * NCH + cc + q) * Hn + h;
        Af[q] = Ac[idx];
        Bf[q] = Bc[idx];
      }
#pragma unroll
      for (int q = 0; q < 8; ++q) hprev = Af[q] * hprev + Bf[q];
    }
    for (; cc < c; ++cc) {
      size_t idx = (size_t)(b * NCH + cc) * Hn + h;
      hprev = Ac[idx] * hprev + Bc[idx];
    }
  }

  // ---- scan phase (no barriers) ----
  for (int j = 0; j < CHUNK; ++j) {
    int t = c * CHUNK + j;
    int s = dir ? (Sn - 1 - t) : t;
    const unsigned short* p = pre + (size_t)(b * Sn + s) * 2048;
    float a, bv;
    gate_ab(bf2f(p[h]), bf2f(p[1024 + h]), a, bv);
    hprev = a * hprev + bv;
    hsl[j][h] = f2bf(hprev);
  }
  __syncthreads();

  // ---- LN phase: wave wv handles rows 2wv, 2wv+1 (round-10 exact) ----
  const int lane = h & 63;
  const int wv   = h >> 6;
  float gm[16], bt[16];
  {
    const float4* gp = reinterpret_cast<const float4*>(gamma);
    const float4* bp = reinterpret_cast<const float4*>(beta);
#pragma unroll
    for (int half = 0; half < 2; ++half) {
      int base = half * 128 + lane * 2;
#pragma unroll
      for (int i = 0; i < 2; ++i) {
        float4 g4 = gp[base + i], b4 = bp[base + i];
        int o = half * 8 + i * 4;
        gm[o+0] = g4.x; gm[o+1] = g4.y; gm[o+2] = g4.z; gm[o+3] = g4.w;
        bt[o+0] = b4.x; bt[o+1] = b4.y; bt[o+2] = b4.z; bt[o+3] = b4.w;
      }
    }
  }

  for (int rr = 0; rr < 2; ++rr) {
    const int j = wv * 2 + rr;
    const int t = c * CHUNK + j;
    const int s = dir ? (Sn - 1 - t) : t;
    const size_t row = (size_t)(b * Sn + s);

    const uint4* rp = reinterpret_cast<const uint4*>(&hsl[j][0]);
    uint4 q0 = rp[lane], q1 = rp[64 + lane];
    uint32_t uw[8] = {q0.x, q0.y, q0.z, q0.w, q1.x, q1.y, q1.z, q1.w};
    float v[16];
#pragma unroll
    for (int k = 0; k < 8; ++k) {
      v[2*k]   = bf2f((unsigned short)(uw[k] & 0xffffu));
      v[2*k+1] = bf2f((unsigned short)(uw[k] >> 16));
    }
    if (resid) {
      const uint4* rf = reinterpret_cast<const uint4*>(resid + row * Hn);
      uint4 r0v = rf[lane], r1v = rf[64 + lane];
      uint32_t rw[8] = {r0v.x, r0v.y, r0v.z, r0v.w, r1v.x, r1v.y, r1v.z, r1v.w};
#pragma unroll
      for (int k = 0; k < 8; ++k) {
        v[2*k]   += bf2f((unsigned short)(rw[k] & 0xffffu));
        v[2*k+1] += bf2f((unsigned short)(rw[k] >> 16));
      }
    }
    float s1 = 0.0f, s2 = 0.0f;
#pragma unroll
    for (int m = 0; m < 16; ++m) { s1 += v[m]; s2 += v[m] * v[m]; }
#pragma unroll
    for (int off = 1; off < 64; off <<= 1) {
      s1 += __shfl_xor(s1, off);
      s2 += __shfl_xor(s2, off);
    }
    float mu  = s1 * (1.0f / Hn);
    float var = s2 * (1.0f / Hn) - mu * mu;
    float rs  = rsqrtf(var + 1e-5f);

    float o[16];
#pragma unroll
    for (int m = 0; m < 16; ++m) o[m] = (v[m] - mu) * rs * gm[m] + bt[m];

    uint4* ob = reinterpret_cast<uint4*>(out_bf + row * bf_stride + bf_off);
    uint4 w0, w1;
    w0.x = f2bf(o[0])  | ((u32)f2bf(o[1])  << 16);
    w0.y = f2bf(o[2])  | ((u32)f2bf(o[3])  << 16);
    w0.z = f2bf(o[4])  | ((u32)f2bf(o[5])  << 16);
    w0.w = f2bf(o[6])  | ((u32)f2bf(o[7])  << 16);
    w1.x = f2bf(o[8])  | ((u32)f2bf(o[9])  << 16);
    w1.y = f2bf(o[10]) | ((u32)f2bf(o[11]) << 16);
    w1.z = f2bf(o[12]) | ((u32)f2bf(o[13]) << 16);
    w1.w = f2bf(o[14]) | ((u32)f2bf(o[15]) << 16);
    ob[lane]      = w0;
    ob[64 + lane] = w1;
  }
}

// ---------------- launcher ----------------
extern "C" void kernel_launch(void* const* d_in, const int* in_sizes, int n_in,
                              void* d_out, int out_size, void* d_ws, size_t ws_size,
                              hipStream_t stream) {
  const float* x        = (const float*)d_in[0];
  const float* fwd_Wz   = (const float*)d_in[1];
  const float* fwd_bz   = (const float*)d_in[2];
  const float* fwd_Wh   = (const float*)d_in[3];
  const float* fwd_bh   = (const float*)d_in[4];
  const float* bwd_Wz   = (const float*)d_in[5];
  const float* bwd_bz   = (const float*)d_in[6];
  const float* bwd_Wh   = (const float*)d_in[7];
  const float* bwd_bh   = (const float*)d_in[8];
  const float* fusion_W = (const float*)d_in[9];
  const float* fusion_b = (const float*)d_in[10];
  const float* gamma    = (const float*)d_in[11];
  const float* beta     = (const float*)d_in[12];
  float* out = (float*)d_out;

  // workspace layout (pre bf16; actf/hs/pref slots retained but unused)
  unsigned short* WzA    = (unsigned short*)d_ws;              // 2*4*1024*1024
  unsigned short* WhA    = WzA + 8ULL * 1024 * 1024;           // 2*4*1024*1024
  unsigned short* fusWbf = WhA + 8ULL * 1024 * 1024;           // 1024*2048
  unsigned short* xbf    = fusWbf + 2ULL * 1024 * 1024;        // 8192*1024
  unsigned short* actbf  = xbf + 8ULL * 1024 * 1024;           // 8192*1024 (GEMM in + resid)
  unsigned short* combbf = actbf + 8ULL * 1024 * 1024;         // 8192*2048
  float* actf = (float*)(combbf + 16ULL * 1024 * 1024);        // unused (layout keep)
  float* pre  = actf + 8ULL * 1024 * 1024;                     // 8192*2048 (bf16 uses half)
  float* hs   = pre + 16ULL * 1024 * 1024;                     // unused (layout keep)
  float* Ac   = hs + 8ULL * 1024 * 1024;                       // 4*NCH*1024
  float* Bc   = Ac + (size_t)Bn * NCH * Hn;
  float* pref = Bc + (size_t)Bn * NCH * Hn;                    // unused (layout keep)
  size_t need = (size_t)((char*)(pref + (size_t)Bn * NCH * Hn) - (char*)d_ws);
  if (ws_size < need) return;
  unsigned short* prebf = (unsigned short*)pre;

  // one fused cast dispatch (was 6)
  cast_all<<<26624, 256, 0, stream>>>(
      fwd_Wz, bwd_Wz, fwd_Wh, bwd_Wh, fusion_W, x,
      WzA, WzA + 4ULL * 1024 * 1024, WhA, WhA + 4ULL * 1024 * 1024, fusWbf, xbf);

  for (int d = 0; d < 2; ++d) {
    const float* bz = d ? bwd_bz : fwd_bz;
    const float* bh = d ? bwd_bh : fwd_bh;
    for (int l = 0; l < Ln; ++l) {
      const unsigned short* a_in = (l == 0) ? xbf : actbf;
      const unsigned short* Wlo = WzA + (size_t)(d * 4 + l) * 1024 * 1024;
      const unsigned short* Whi = WhA + (size_t)(d * 4 + l) * 1024 * 1024;
      gemm_t<8><<<dim3(Mn / 256, 2048 / 256), 512, 0, stream>>>(
          a_in, Wlo, Whi, bz + l * 1024, bh + l * 1024, 1024,
          nullptr, prebf, 2048, 1024);
      scan_p1<<<Bn * NCH * 4, 256, 0, stream>>>(prebf, Ac, Bc, d);
      if (l < Ln - 1)
        scan_p3_ln<<<Bn * NCH, 1024, 0, stream>>>(
            prebf, Ac, Bc, (l == 0) ? nullptr : actbf, gamma, beta,
            actbf, 1024, 0, d);
      else
        scan_p3_ln<<<Bn * NCH, 1024, 0, stream>>>(
            prebf, Ac, Bc, actbf, gamma, beta,
            combbf, 2048, d * 1024, d);
    }
  }
  // fusion: out = comb(bf16) @ fusion_W^T + fusion_b (f32 output, BM=128 -> 256 blocks)
  gemm_t<4><<<dim3(Mn / 128, 1024 / 256), 512, 0, stream>>>(
      combbf, fusWbf, fusWbf, fusion_b, fusion_b, 1 << 30, out, nullptr, 1024, 2048);
}

// Round 13
// 598.999 us; speedup vs baseline: 1.2622x; 1.1369x over previous
//
#include <hip/hip_runtime.h>
#include <stdint.h>

#define Bn 4
#define Sn 2048
#define Hn 1024
#define Ln 4
#define Mn (Bn*Sn)          // 8192 rows
#define CHUNK 32
#define NCH (Sn/CHUNK)      // 64

typedef __bf16 bf16x8 __attribute__((ext_vector_type(8)));
typedef float  f32x4  __attribute__((ext_vector_type(4)));
typedef uint32_t u32;

__device__ __forceinline__ unsigned short f2bf(float f) {
  uint32_t u = __float_as_uint(f);
  uint32_t r = (u + 0x7FFFu + ((u >> 16) & 1u)) >> 16;
  return (unsigned short)r;
}
__device__ __forceinline__ float bf2f(unsigned short u) {
  return __uint_as_float(((uint32_t)u) << 16);
}

__device__ __forceinline__ void gload_lds16(const void* g, void* l) {
  __builtin_amdgcn_global_load_lds((const __attribute__((address_space(1))) void*)g,
                                   (__attribute__((address_space(3))) void*)l, 16, 0, 0);
}

// ---------------- pointwise gate ----------------
__device__ __forceinline__ void gate_ab(float zp, float hp, float& a, float& bv) {
  float z  = 1.0f / (1.0f + __expf(-zp));
  float e  = __expf(-2.0f * fabsf(hp));
  float th = (1.0f - e) / (1.0f + e);
  th = (hp >= 0.0f) ? th : -th;
  a  = fminf(fmaxf(1.0f - z, 1e-8f), 1.0f - 1e-8f);
  bv = z * th;
}

// ---------------- single fused cast f32 -> bf16 (6 dispatches -> 1) ----------------
__global__ __launch_bounds__(256) void cast_all(
    const float* __restrict__ s0, const float* __restrict__ s1,
    const float* __restrict__ s2, const float* __restrict__ s3,
    const float* __restrict__ s4, const float* __restrict__ s5,
    unsigned short* __restrict__ d0, unsigned short* __restrict__ d1,
    unsigned short* __restrict__ d2, unsigned short* __restrict__ d3,
    unsigned short* __restrict__ d4, unsigned short* __restrict__ d5) {
  long i = (long)blockIdx.x * 256 + threadIdx.x;   // grid = 6815744 / 256
  const float* s; unsigned short* d; long off;
  if      (i < 1048576) { s = s0; d = d0; off = i; }
  else if (i < 2097152) { s = s1; d = d1; off = i - 1048576; }
  else if (i < 3145728) { s = s2; d = d2; off = i - 2097152; }
  else if (i < 4194304) { s = s3; d = d3; off = i - 3145728; }
  else if (i < 4718592) { s = s4; d = d4; off = i - 4194304; }
  else                  { s = s5; d = d5; off = i - 4718592; }
  float4 v = reinterpret_cast<const float4*>(s)[off];
  ushort4 o;
  o.x = f2bf(v.x); o.y = f2bf(v.y); o.z = f2bf(v.z); o.w = f2bf(v.w);
  reinterpret_cast<ushort4*>(d)[off] = o;
}

// ---------------- GEMM ----------------
// K-loop frozen since round 8 (layer ~42.5 us / 810 TF). ROUND-13: GATE variant —
// the layer GEMM's B-tile stages 128 Wz rows (LDS rows 0-127) + the MATCHING 128
// Wh rows (rows 128-255); grid bn = 8 panels of 128 col-pairs. Thread col-fragments
// n in {0,1} are z, n in {2,3} the same cols' h-tilde -> gate_ab computed
// THREAD-LOCALLY in the epilogue from f32 accumulators, writing (a, bv) bf16 in
// pre's [z|h] layout. p1/p3 then fold (a,bv) with 2 fma/step — the duplicated
// 2-exp gate math (2x 8.4M evals/layer-dir) is eliminated. Only the B base
// pointers and the upper-half B ds_read offsets ({0,1024,8192,9216}) differ from
// the generic path; K-loop body, swizzle, staging count identical.

#define DSR(d, b, imm) \
  asm volatile("ds_read_b128 %0, %1 offset:%c2" : "=&v"(d) : "v"(b), "i"(imm))

#define VMW(n) do { \
    asm volatile("s_waitcnt vmcnt(" #n ")"); \
    __builtin_amdgcn_sched_barrier(0); \
  } while (0)

#define LGKM(n) do { \
    asm volatile("s_waitcnt lgkmcnt(" #n ")"); \
    __builtin_amdgcn_sched_barrier(0); \
  } while (0)

#define DSRA4(ARR, off) do { \
    DSR(ARR[0], baseA, (off)); \
    DSR(ARR[1], baseA, (off) + 1024); \
    DSR(ARR[2], baseA, (off) + 2048); \
    DSR(ARR[3], baseA, (off) + 3072); \
  } while (0)

#define DSRB4(ARR, off) do { \
    DSR(ARR[0], baseB, (off)); \
    DSR(ARR[1], baseB, (off) + 1024); \
    DSR(ARR[2], baseB, (off) + OB2); \
    DSR(ARR[3], baseB, (off) + OB3); \
  } while (0)

#define CL(ARR, BARR, MB) do { \
    __builtin_amdgcn_s_setprio(1); \
    _Pragma("unroll") \
    for (int _m = 0; _m < 4; ++_m) { \
      _Pragma("unroll") \
      for (int _n = 0; _n < 4; ++_n) \
        acc[(MB) + _m][_n] = __builtin_amdgcn_mfma_f32_16x16x32_bf16( \
            ARR[_m], BARR[_n], acc[(MB) + _m][_n], 0, 0, 0); \
    } \
    __builtin_amdgcn_s_setprio(0); \
  } while (0)

#define BODY(buf) do { \
    if constexpr (MF == 8) { \
      DSRA4(aA, ((buf) * 2 + 0) * RGA); \
      DSRB4(b0, ((buf) * 2 + 0) * 16384); \
      DSRA4(aB, ((buf) * 2 + 0) * RGA + 4096); \
      LGKM(4); \
      CL(aA, b0, 0); \
      DSRB4(b1, ((buf) * 2 + 1) * 16384); \
      LGKM(4); \
      CL(aB, b0, 4); \
      DSRA4(aA, ((buf) * 2 + 1) * RGA); \
      LGKM(4); \
      DSRA4(aB, ((buf) * 2 + 1) * RGA + 4096); \
      LGKM(4); \
      CL(aA, b1, 0); \
      LGKM(0); \
      CL(aB, b1, 4); \
    } else { \
      DSRA4(aA, ((buf) * 2 + 0) * RGA); \
      DSRB4(b0, ((buf) * 2 + 0) * 16384); \
      DSRA4(aB, ((buf) * 2 + 1) * RGA); \
      LGKM(4); \
      CL(aA, b0, 0); \
      DSRB4(b1, ((buf) * 2 + 1) * 16384); \
      LGKM(0); \
      CL(aB, b1, 0); \
    } \
  } while (0)

template<int MF, bool GATE>
__global__ __launch_bounds__(512, 2) void gemm_t(
    const unsigned short* __restrict__ act,  // M x K
    const unsigned short* __restrict__ Wlo,  // GATE: Wz ; else rows [0, Nsplit)
    const unsigned short* __restrict__ Whi,  // GATE: Wh ; else rows [Nsplit, N)
    const float* __restrict__ bias0, const float* __restrict__ bias1,
    int Nsplit, float* __restrict__ out, unsigned short* __restrict__ outbf,
    int Ndim, int K) {
  constexpr int BMR = MF * 32;            // 256 or 128 rows
  constexpr int RGA = BMR * 64;           // A (buf,kh)-region bytes
  constexpr int OB2 = GATE ? 8192 : 2048; // B fragment-2 byte offset
  constexpr int OB3 = GATE ? 9216 : 3072; // B fragment-3 byte offset
  __shared__ unsigned char smA[4 * RGA];
  __shared__ unsigned char smB[65536];
  const int tid  = threadIdx.x;
  const int lane = tid & 63;
  const int w    = tid >> 6;           // 0..7
  const int waveM = w >> 2;            // 0..1
  const int waveN = w & 3;             // 0..3
  const int bm = blockIdx.x, bn = blockIdx.y;

  const int swz  = (((lane >> 4) ^ ((lane >> 1) & 3)) << 4);
  const int aoff = (waveM * (MF * 16) + (lane & 15)) * 64 + swz;
  const int boff = ((GATE ? waveN * 32 : waveN * 64) + (lane & 15)) * 64 + swz;

  const u32 baseA = (u32)(size_t)(void*)&smA[0] + (u32)aoff;
  const u32 baseB = (u32)(size_t)(void*)&smB[0] + (u32)boff;

  const int srow = tid >> 2;
  const int slog = (tid & 3) ^ ((srow >> 1) & 3);
  const unsigned short* aS0 = act + (size_t)(bm * BMR + srow) * K + slog * 8;
  const unsigned short* aS1 = aS0 + (size_t)128 * K;   // used only when MF==8
  const unsigned short *bS0, *bS1;
  if constexpr (GATE) {
    bS0 = Wlo + (size_t)(bn * 128 + srow) * K + slog * 8;   // z-weights -> B rows 0..127
    bS1 = Whi + (size_t)(bn * 128 + srow) * K + slog * 8;   // h-weights -> B rows 128..255
  } else {
    const unsigned short* Wp; int nbase;
    if (bn * 256 < Nsplit) { Wp = Wlo; nbase = bn * 256; }
    else                   { Wp = Whi; nbase = bn * 256 - Nsplit; }
    bS0 = Wp + (size_t)(nbase + srow) * K + slog * 8;
    bS1 = bS0 + (size_t)128 * K;
  }
  const int wB = w * 1024;

  f32x4 acc[MF][4];
#pragma unroll
  for (int m = 0; m < MF; ++m)
#pragma unroll
    for (int n = 0; n < 4; ++n) acc[m][n] = (f32x4)0.0f;

  bf16x8 aA[4], aB[4], b0[4], b1[4];

  auto STG4 = [&](int t, int buf) {
#pragma unroll
    for (int kh = 0; kh < 2; ++kh) {
      unsigned char* ra = smA + (buf * 2 + kh) * RGA;
      gload_lds16(aS0 + (size_t)t * 64 + kh * 32, ra + wB);
      if constexpr (MF == 8)
        gload_lds16(aS1 + (size_t)t * 64 + kh * 32, ra + 8192 + wB);
      unsigned char* rb = smB + (buf * 2 + kh) * 16384;
      gload_lds16(bS0 + (size_t)t * 64 + kh * 32, rb + wB);
      gload_lds16(bS1 + (size_t)t * 64 + kh * 32, rb + 8192 + wB);
    }
  };

  const int nkt   = K >> 6;   // K-tiles (even)
  const int niter = nkt >> 1;

  STG4(0, 0);
  VMW(0);
  __builtin_amdgcn_s_barrier();

  for (int j = 0; j < niter - 1; ++j) {
    STG4(2 * j + 1, 1); BODY(0); VMW(0); __builtin_amdgcn_s_barrier();
    STG4(2 * j + 2, 0); BODY(1); VMW(0); __builtin_amdgcn_s_barrier();
  }
  STG4(nkt - 1, 1); BODY(0); VMW(0); __builtin_amdgcn_s_barrier();
  BODY(1);

  const int rowBase = bm * BMR + waveM * (MF * 16);
  if constexpr (GATE) {
    // epilogue: gate from f32 accumulators; write a -> pre[row, col], bv -> pre[row, 1024+col]
#pragma unroll
    for (int n = 0; n < 2; ++n) {
      const int col = bn * 128 + waveN * 32 + n * 16 + (lane & 15);
      const float bz = bias0[col];
      const float bh = bias1[col];
#pragma unroll
      for (int m = 0; m < MF; ++m) {
#pragma unroll
        for (int r = 0; r < 4; ++r) {
          int row = rowBase + m * 16 + (lane >> 4) * 4 + r;
          float a, bv;
          gate_ab(acc[m][n][r] + bz, acc[m][n + 2][r] + bh, a, bv);
          outbf[(size_t)row * 2048 + col]        = f2bf(a);
          outbf[(size_t)row * 2048 + 1024 + col] = f2bf(bv);
        }
      }
    }
  } else {
    const int colBase = bn * 256 + waveN * 64;
#pragma unroll
    for (int m = 0; m < MF; ++m) {
#pragma unroll
      for (int n = 0; n < 4; ++n) {
        int col = colBase + n * 16 + (lane & 15);
        float bv = (col < Nsplit) ? bias0[col] : bias1[col - Nsplit];
        if (outbf) {
#pragma unroll
          for (int r = 0; r < 4; ++r) {
            int row = rowBase + m * 16 + (lane >> 4) * 4 + r;
            outbf[(size_t)row * Ndim + col] = f2bf(acc[m][n][r] + bv);
          }
        } else {
#pragma unroll
          for (int r = 0; r < 4; ++r) {
            int row = rowBase + m * 16 + (lane >> 4) * 4 + r;
            out[(size_t)row * Ndim + col] = acc[m][n][r] + bv;
          }
        }
      }
    }
  }
}

// ---------------- scan pass 1: pure fold over precomputed (a, bv) ----------------
__global__ __launch_bounds__(256) void scan_p1(const unsigned short* __restrict__ pre,
                                               float* __restrict__ Ac, float* __restrict__ Bc,
                                               int dir) {
  int tid = threadIdx.x;
  int bid = blockIdx.x;
  int ht = bid & 3;
  int c  = (bid >> 2) & (NCH - 1);
  int b  = bid >> 8;
  int h  = ht * 256 + tid;
  float Aa = 1.0f, Bb = 0.0f;
  for (int j = 0; j < CHUNK; ++j) {
    int t = c * CHUNK + j;
    int s = dir ? (Sn - 1 - t) : t;
    const unsigned short* p = pre + (size_t)(b * Sn + s) * 2048;
    float a  = bf2f(p[h]);
    float bv = bf2f(p[1024 + h]);
    Aa = a * Aa;
    Bb = a * Bb + bv;
  }
  Ac[(size_t)(b * NCH + c) * Hn + h] = Aa;
  Bc[(size_t)(b * NCH + c) * Hn + h] = Bb;
}

// ---------------- scan pass 3 + prefix + LayerNorm ----------------
// Round-12 structure (1024 threads, prefix fold replaces scan_mid) with the scan
// phase reduced to a pure (a, bv) fold — gate math moved to the GEMM epilogue.
__global__ __launch_bounds__(1024) void scan_p3_ln(
    const unsigned short* __restrict__ pre,
    const float* __restrict__ Ac, const float* __restrict__ Bc,
    const unsigned short* __restrict__ resid,
    const float* __restrict__ gamma, const float* __restrict__ beta,
    unsigned short* __restrict__ out_bf,
    int bf_stride, int bf_off, int dir) {
  __shared__ unsigned short hsl[CHUNK][Hn];   // 64 KB
  const int h = threadIdx.x;
  const int c = blockIdx.x & (NCH - 1);
  const int b = blockIdx.x >> 6;              // NCH = 64

  // ---- prefix fold over chunks 0..c-1 (same fold order as old scan_mid) ----
  float hprev = 0.0f;
  {
    int cc = 0;
    for (; cc + 8 <= c; cc += 8) {
      float Af[8], Bf[8];
#pragma unroll
      for (int q = 0; q < 8; ++q) {
        size_t idx = (size_t)(b * NCH + cc + q) * Hn + h;
        Af[q] = Ac[idx];
        Bf[q] = Bc[idx];
      }
#pragma unroll
      for (int q = 0; q < 8; ++q) hprev = Af[q] * hprev + Bf[q];
    }
    for (; cc < c; ++cc) {
      size_t idx = (size_t)(b * NCH + cc) * Hn + h;
      hprev = Ac[idx] * hprev + Bc[idx];
    }
  }

  // ---- scan phase (no barriers; pure fold) ----
  for (int j = 0; j < CHUNK; ++j) {
    int t = c * CHUNK + j;
    int s = dir ? (Sn - 1 - t) : t;
    const unsigned short* p = pre + (size_t)(b * Sn + s) * 2048;
    float a  = bf2f(p[h]);
    float bv = bf2f(p[1024 + h]);
    hprev = a * hprev + bv;
    hsl[j][h] = f2bf(hprev);
  }
  __syncthreads();

  // ---- LN phase: wave wv handles rows 2wv, 2wv+1 ----
  const int lane = h & 63;
  const int wv   = h >> 6;
  float gm[16], bt[16];
  {
    const float4* gp = reinterpret_cast<const float4*>(gamma);
    const float4* bp = reinterpret_cast<const float4*>(beta);
#pragma unroll
    for (int half = 0; half < 2; ++half) {
      int base = half * 128 + lane * 2;
#pragma unroll
      for (int i = 0; i < 2; ++i) {
        float4 g4 = gp[base + i], b4 = bp[base + i];
        int o = half * 8 + i * 4;
        gm[o+0] = g4.x; gm[o+1] = g4.y; gm[o+2] = g4.z; gm[o+3] = g4.w;
        bt[o+0] = b4.x; bt[o+1] = b4.y; bt[o+2] = b4.z; bt[o+3] = b4.w;
      }
    }
  }

  for (int rr = 0; rr < 2; ++rr) {
    const int j = wv * 2 + rr;
    const int t = c * CHUNK + j;
    const int s = dir ? (Sn - 1 - t) : t;
    const size_t row = (size_t)(b * Sn + s);

    const uint4* rp = reinterpret_cast<const uint4*>(&hsl[j][0]);
    uint4 q0 = rp[lane], q1 = rp[64 + lane];
    uint32_t uw[8] = {q0.x, q0.y, q0.z, q0.w, q1.x, q1.y, q1.z, q1.w};
    float v[16];
#pragma unroll
    for (int k = 0; k < 8; ++k) {
      v[2*k]   = bf2f((unsigned short)(uw[k] & 0xffffu));
      v[2*k+1] = bf2f((unsigned short)(uw[k] >> 16));
    }
    if (resid) {
      const uint4* rf = reinterpret_cast<const uint4*>(resid + row * Hn);
      uint4 r0v = rf[lane], r1v = rf[64 + lane];
      uint32_t rw[8] = {r0v.x, r0v.y, r0v.z, r0v.w, r1v.x, r1v.y, r1v.z, r1v.w};
#pragma unroll
      for (int k = 0; k < 8; ++k) {
        v[2*k]   += bf2f((unsigned short)(rw[k] & 0xffffu));
        v[2*k+1] += bf2f((unsigned short)(rw[k] >> 16));
      }
    }
    float s1 = 0.0f, s2 = 0.0f;
#pragma unroll
    for (int m = 0; m < 16; ++m) { s1 += v[m]; s2 += v[m] * v[m]; }
#pragma unroll
    for (int off = 1; off < 64; off <<= 1) {
      s1 += __shfl_xor(s1, off);
      s2 += __shfl_xor(s2, off);
    }
    float mu  = s1 * (1.0f / Hn);
    float var = s2 * (1.0f / Hn) - mu * mu;
    float rs  = rsqrtf(var + 1e-5f);

    float o[16];
#pragma unroll
    for (int m = 0; m < 16; ++m) o[m] = (v[m] - mu) * rs * gm[m] + bt[m];

    uint4* ob = reinterpret_cast<uint4*>(out_bf + row * bf_stride + bf_off);
    uint4 w0, w1;
    w0.x = f2bf(o[0])  | ((u32)f2bf(o[1])  << 16);
    w0.y = f2bf(o[2])  | ((u32)f2bf(o[3])  << 16);
    w0.z = f2bf(o[4])  | ((u32)f2bf(o[5])  << 16);
    w0.w = f2bf(o[6])  | ((u32)f2bf(o[7])  << 16);
    w1.x = f2bf(o[8])  | ((u32)f2bf(o[9])  << 16);
    w1.y = f2bf(o[10]) | ((u32)f2bf(o[11]) << 16);
    w1.z = f2bf(o[12]) | ((u32)f2bf(o[13]) << 16);
    w1.w = f2bf(o[14]) | ((u32)f2bf(o[15]) << 16);
    ob[lane]      = w0;
    ob[64 + lane] = w1;
  }
}

// ---------------- launcher ----------------
extern "C" void kernel_launch(void* const* d_in, const int* in_sizes, int n_in,
                              void* d_out, int out_size, void* d_ws, size_t ws_size,
                              hipStream_t stream) {
  const float* x        = (const float*)d_in[0];
  const float* fwd_Wz   = (const float*)d_in[1];
  const float* fwd_bz   = (const float*)d_in[2];
  const float* fwd_Wh   = (const float*)d_in[3];
  const float* fwd_bh   = (const float*)d_in[4];
  const float* bwd_Wz   = (const float*)d_in[5];
  const float* bwd_bz   = (const float*)d_in[6];
  const float* bwd_Wh   = (const float*)d_in[7];
  const float* bwd_bh   = (const float*)d_in[8];
  const float* fusion_W = (const float*)d_in[9];
  const float* fusion_b = (const float*)d_in[10];
  const float* gamma    = (const float*)d_in[11];
  const float* beta     = (const float*)d_in[12];
  float* out = (float*)d_out;

  // workspace layout (pre holds (a,bv) bf16; actf/hs/pref slots unused)
  unsigned short* WzA    = (unsigned short*)d_ws;              // 2*4*1024*1024
  unsigned short* WhA    = WzA + 8ULL * 1024 * 1024;           // 2*4*1024*1024
  unsigned short* fusWbf = WhA + 8ULL * 1024 * 1024;           // 1024*2048
  unsigned short* xbf    = fusWbf + 2ULL * 1024 * 1024;        // 8192*1024
  unsigned short* actbf  = xbf + 8ULL * 1024 * 1024;           // 8192*1024 (GEMM in + resid)
  unsigned short* combbf = actbf + 8ULL * 1024 * 1024;         // 8192*2048
  float* actf = (float*)(combbf + 16ULL * 1024 * 1024);        // unused (layout keep)
  float* pre  = actf + 8ULL * 1024 * 1024;                     // 8192*2048 (bf16 uses half)
  float* hs   = pre + 16ULL * 1024 * 1024;                     // unused (layout keep)
  float* Ac   = hs + 8ULL * 1024 * 1024;                       // 4*NCH*1024
  float* Bc   = Ac + (size_t)Bn * NCH * Hn;
  float* pref = Bc + (size_t)Bn * NCH * Hn;                    // unused (layout keep)
  size_t need = (size_t)((char*)(pref + (size_t)Bn * NCH * Hn) - (char*)d_ws);
  if (ws_size < need) return;
  unsigned short* prebf = (unsigned short*)pre;

  // one fused cast dispatch
  cast_all<<<26624, 256, 0, stream>>>(
      fwd_Wz, bwd_Wz, fwd_Wh, bwd_Wh, fusion_W, x,
      WzA, WzA + 4ULL * 1024 * 1024, WhA, WhA + 4ULL * 1024 * 1024, fusWbf, xbf);

  for (int d = 0; d < 2; ++d) {
    const float* bz = d ? bwd_bz : fwd_bz;
    const float* bh = d ? bwd_bh : fwd_bh;
    for (int l = 0; l < Ln; ++l) {
      const unsigned short* a_in = (l == 0) ? xbf : actbf;
      const unsigned short* Wlo = WzA + (size_t)(d * 4 + l) * 1024 * 1024;
      const unsigned short* Whi = WhA + (size_t)(d * 4 + l) * 1024 * 1024;
      gemm_t<8, true><<<dim3(Mn / 256, 8), 512, 0, stream>>>(
          a_in, Wlo, Whi, bz + l * 1024, bh + l * 1024, 1024,
          nullptr, prebf, 2048, 1024);
      scan_p1<<<Bn * NCH * 4, 256, 0, stream>>>(prebf, Ac, Bc, d);
      if (l < Ln - 1)
        scan_p3_ln<<<Bn * NCH, 1024, 0, stream>>>(
            prebf, Ac, Bc, (l == 0) ? nullptr : actbf, gamma, beta,
            actbf, 1024, 0, d);
      else
        scan_p3_ln<<<Bn * NCH, 1024, 0, stream>>>(
            prebf, Ac, Bc, actbf, gamma, beta,
            combbf, 2048, d * 1024, d);
    }
  }
  // fusion: out = comb(bf16) @ fusion_W^T + fusion_b (f32 output, BM=128 -> 256 blocks)
  gemm_t<4, false><<<dim3(Mn / 128, 1024 / 256), 512, 0, stream>>>(
      combbf, fusWbf, fusWbf, fusion_b, fusion_b, 1 << 30, out, nullptr, 1024, 2048);
}

// Round 15
// 570.878 us; speedup vs baseline: 1.3243x; 1.0493x over previous
//
#include <hip/hip_runtime.h>
#include <stdint.h>

#define Bn 4
#define Sn 2048
#define Hn 1024
#define Ln 4
#define Mn (Bn*Sn)          // 8192 rows
#define CHUNK 32
#define NCH (Sn/CHUNK)      // 64

typedef __bf16 bf16x8 __attribute__((ext_vector_type(8)));
typedef float  f32x4  __attribute__((ext_vector_type(4)));
typedef uint32_t u32;

__device__ __forceinline__ unsigned short f2bf(float f) {
  uint32_t u = __float_as_uint(f);
  uint32_t r = (u + 0x7FFFu + ((u >> 16) & 1u)) >> 16;
  return (unsigned short)r;
}
__device__ __forceinline__ float bf2f(unsigned short u) {
  return __uint_as_float(((uint32_t)u) << 16);
}

__device__ __forceinline__ void gload_lds16(const void* g, void* l) {
  __builtin_amdgcn_global_load_lds((const __attribute__((address_space(1))) void*)g,
                                   (__attribute__((address_space(3))) void*)l, 16, 0, 0);
}

// ---------------- pointwise gate ----------------
__device__ __forceinline__ void gate_ab(float zp, float hp, float& a, float& bv) {
  float z  = 1.0f / (1.0f + __expf(-zp));
  float e  = __expf(-2.0f * fabsf(hp));
  float th = (1.0f - e) / (1.0f + e);
  th = (hp >= 0.0f) ? th : -th;
  a  = fminf(fmaxf(1.0f - z, 1e-8f), 1.0f - 1e-8f);
  bv = z * th;
}

// ---------------- single fused cast f32 -> bf16 ----------------
__global__ __launch_bounds__(256) void cast_all(
    const float* __restrict__ s0, const float* __restrict__ s1,
    const float* __restrict__ s2, const float* __restrict__ s3,
    const float* __restrict__ s4, const float* __restrict__ s5,
    unsigned short* __restrict__ d0, unsigned short* __restrict__ d1,
    unsigned short* __restrict__ d2, unsigned short* __restrict__ d3,
    unsigned short* __restrict__ d4, unsigned short* __restrict__ d5) {
  long i = (long)blockIdx.x * 256 + threadIdx.x;   // grid = 6815744 / 256
  const float* s; unsigned short* d; long off;
  if      (i < 1048576) { s = s0; d = d0; off = i; }
  else if (i < 2097152) { s = s1; d = d1; off = i - 1048576; }
  else if (i < 3145728) { s = s2; d = d2; off = i - 2097152; }
  else if (i < 4194304) { s = s3; d = d3; off = i - 3145728; }
  else if (i < 4718592) { s = s4; d = d4; off = i - 4194304; }
  else                  { s = s5; d = d5; off = i - 4718592; }
  float4 v = reinterpret_cast<const float4*>(s)[off];
  ushort4 o;
  o.x = f2bf(v.x); o.y = f2bf(v.y); o.z = f2bf(v.z); o.w = f2bf(v.w);
  reinterpret_cast<ushort4*>(d)[off] = o;
}

// ---------------- GEMM ----------------
// K-loop frozen since round 8. GATE epilogue: gates from f32 accumulators,
// (a,bv) bf16 writes, AND per-chunk scan composites Ac/Bc.
// ROUND-15 FIX: round 14 combined each thread's mm=0/mm=1 segments BEFORE the
// cross-q butterfly — but those segments (rows q*4..+3 and 16+q*4..+3) are not
// contiguous in s, so the non-commutative composition was element-order-wrong
// (absmax 0.18). Correct order: per 16-row fragment mm, fold r (dir-aware) then
// ordered butterfly across q (fragment rows ARE q-major contiguous) -> every lane
// holds the fragment composite; THEN combine mm=0 (rows 0-15) with mm=1 (16-31).
// Composition uses the bf16-ROUNDED (a,bv) — identical inputs to the old scan_p1;
// only FP association differs (ulp).

#define DSR(d, b, imm) \
  asm volatile("ds_read_b128 %0, %1 offset:%c2" : "=&v"(d) : "v"(b), "i"(imm))

#define VMW(n) do { \
    asm volatile("s_waitcnt vmcnt(" #n ")"); \
    __builtin_amdgcn_sched_barrier(0); \
  } while (0)

#define LGKM(n) do { \
    asm volatile("s_waitcnt lgkmcnt(" #n ")"); \
    __builtin_amdgcn_sched_barrier(0); \
  } while (0)

#define DSRA4(ARR, off) do { \
    DSR(ARR[0], baseA, (off)); \
    DSR(ARR[1], baseA, (off) + 1024); \
    DSR(ARR[2], baseA, (off) + 2048); \
    DSR(ARR[3], baseA, (off) + 3072); \
  } while (0)

#define DSRB4(ARR, off) do { \
    DSR(ARR[0], baseB, (off)); \
    DSR(ARR[1], baseB, (off) + 1024); \
    DSR(ARR[2], baseB, (off) + OB2); \
    DSR(ARR[3], baseB, (off) + OB3); \
  } while (0)

#define CL(ARR, BARR, MB) do { \
    __builtin_amdgcn_s_setprio(1); \
    _Pragma("unroll") \
    for (int _m = 0; _m < 4; ++_m) { \
      _Pragma("unroll") \
      for (int _n = 0; _n < 4; ++_n) \
        acc[(MB) + _m][_n] = __builtin_amdgcn_mfma_f32_16x16x32_bf16( \
            ARR[_m], BARR[_n], acc[(MB) + _m][_n], 0, 0, 0); \
    } \
    __builtin_amdgcn_s_setprio(0); \
  } while (0)

#define BODY(buf) do { \
    if constexpr (MF == 8) { \
      DSRA4(aA, ((buf) * 2 + 0) * RGA); \
      DSRB4(b0, ((buf) * 2 + 0) * 16384); \
      DSRA4(aB, ((buf) * 2 + 0) * RGA + 4096); \
      LGKM(4); \
      CL(aA, b0, 0); \
      DSRB4(b1, ((buf) * 2 + 1) * 16384); \
      LGKM(4); \
      CL(aB, b0, 4); \
      DSRA4(aA, ((buf) * 2 + 1) * RGA); \
      LGKM(4); \
      DSRA4(aB, ((buf) * 2 + 1) * RGA + 4096); \
      LGKM(4); \
      CL(aA, b1, 0); \
      LGKM(0); \
      CL(aB, b1, 4); \
    } else { \
      DSRA4(aA, ((buf) * 2 + 0) * RGA); \
      DSRB4(b0, ((buf) * 2 + 0) * 16384); \
      DSRA4(aB, ((buf) * 2 + 1) * RGA); \
      LGKM(4); \
      CL(aA, b0, 0); \
      DSRB4(b1, ((buf) * 2 + 1) * 16384); \
      LGKM(0); \
      CL(aB, b1, 0); \
    } \
  } while (0)

template<int MF, bool GATE>
__global__ __launch_bounds__(512, 2) void gemm_t(
    const unsigned short* __restrict__ act,  // M x K
    const unsigned short* __restrict__ Wlo,  // GATE: Wz ; else rows [0, Nsplit)
    const unsigned short* __restrict__ Whi,  // GATE: Wh ; else rows [Nsplit, N)
    const float* __restrict__ bias0, const float* __restrict__ bias1,
    int Nsplit, float* __restrict__ out, unsigned short* __restrict__ outbf,
    float* __restrict__ Acp, float* __restrict__ Bcp, int dir,
    int Ndim, int K) {
  constexpr int BMR = MF * 32;            // 256 or 128 rows
  constexpr int RGA = BMR * 64;           // A (buf,kh)-region bytes
  constexpr int OB2 = GATE ? 8192 : 2048;
  constexpr int OB3 = GATE ? 9216 : 3072;
  __shared__ unsigned char smA[4 * RGA];
  __shared__ unsigned char smB[65536];
  const int tid  = threadIdx.x;
  const int lane = tid & 63;
  const int w    = tid >> 6;           // 0..7
  const int waveM = w >> 2;            // 0..1
  const int waveN = w & 3;             // 0..3
  const int bm = blockIdx.x, bn = blockIdx.y;

  const int swz  = (((lane >> 4) ^ ((lane >> 1) & 3)) << 4);
  const int aoff = (waveM * (MF * 16) + (lane & 15)) * 64 + swz;
  const int boff = ((GATE ? waveN * 32 : waveN * 64) + (lane & 15)) * 64 + swz;

  const u32 baseA = (u32)(size_t)(void*)&smA[0] + (u32)aoff;
  const u32 baseB = (u32)(size_t)(void*)&smB[0] + (u32)boff;

  const int srow = tid >> 2;
  const int slog = (tid & 3) ^ ((srow >> 1) & 3);
  const unsigned short* aS0 = act + (size_t)(bm * BMR + srow) * K + slog * 8;
  const unsigned short* aS1 = aS0 + (size_t)128 * K;   // used only when MF==8
  const unsigned short *bS0, *bS1;
  if constexpr (GATE) {
    bS0 = Wlo + (size_t)(bn * 128 + srow) * K + slog * 8;
    bS1 = Whi + (size_t)(bn * 128 + srow) * K + slog * 8;
  } else {
    const unsigned short* Wp; int nbase;
    if (bn * 256 < Nsplit) { Wp = Wlo; nbase = bn * 256; }
    else                   { Wp = Whi; nbase = bn * 256 - Nsplit; }
    bS0 = Wp + (size_t)(nbase + srow) * K + slog * 8;
    bS1 = bS0 + (size_t)128 * K;
  }
  const int wB = w * 1024;

  f32x4 acc[MF][4];
#pragma unroll
  for (int m = 0; m < MF; ++m)
#pragma unroll
    for (int n = 0; n < 4; ++n) acc[m][n] = (f32x4)0.0f;

  bf16x8 aA[4], aB[4], b0[4], b1[4];

  auto STG4 = [&](int t, int buf) {
#pragma unroll
    for (int kh = 0; kh < 2; ++kh) {
      unsigned char* ra = smA + (buf * 2 + kh) * RGA;
      gload_lds16(aS0 + (size_t)t * 64 + kh * 32, ra + wB);
      if constexpr (MF == 8)
        gload_lds16(aS1 + (size_t)t * 64 + kh * 32, ra + 8192 + wB);
      unsigned char* rb = smB + (buf * 2 + kh) * 16384;
      gload_lds16(bS0 + (size_t)t * 64 + kh * 32, rb + wB);
      gload_lds16(bS1 + (size_t)t * 64 + kh * 32, rb + 8192 + wB);
    }
  };

  const int nkt   = K >> 6;
  const int niter = nkt >> 1;

  STG4(0, 0);
  VMW(0);
  __builtin_amdgcn_s_barrier();

  for (int j = 0; j < niter - 1; ++j) {
    STG4(2 * j + 1, 1); BODY(0); VMW(0); __builtin_amdgcn_s_barrier();
    STG4(2 * j + 2, 0); BODY(1); VMW(0); __builtin_amdgcn_s_barrier();
  }
  STG4(nkt - 1, 1); BODY(0); VMW(0); __builtin_amdgcn_s_barrier();
  BODY(1);

  const int rowBase = bm * BMR + waveM * (MF * 16);
  if constexpr (GATE) {
    const int colBase = bn * 128 + waveN * 32;
    const int c0 = lane & 15;
    const int q  = lane >> 4;
    const float bz0 = bias0[colBase + c0],      bh0 = bias1[colBase + c0];
    const float bz1 = bias0[colBase + 16 + c0], bh1 = bias1[colBase + 16 + c0];
    const int batch   = bm >> 3;             // 8 tiles per batch (2048/256)
    const int schunk0 = (bm & 7) * 8;        // s0/32

#pragma unroll
    for (int k = 0; k < 4; ++k) {            // 4 chunks per wave (2 fragments each)
      float CA[2][2], CB[2][2];              // [mm][n] fragment composite (all lanes)
#pragma unroll
      for (int mm = 0; mm < 2; ++mm) {
        const int m = k * 2 + mm;
        float TA[2] = {1.0f, 1.0f}, TB[2] = {0.0f, 0.0f};
#pragma unroll
        for (int r = 0; r < 4; ++r) {
          const int row = rowBase + m * 16 + q * 4 + r;
          float a0, bv0, a1, bv1;
          gate_ab(acc[m][0][r] + bz0, acc[m][2][r] + bh0, a0, bv0);
          gate_ab(acc[m][1][r] + bz1, acc[m][3][r] + bh1, a1, bv1);
          const unsigned short ua0 = f2bf(a0), ua1 = f2bf(a1);
          const unsigned short ub0 = f2bf(bv0), ub1 = f2bf(bv1);
          unsigned short* pr = outbf + (size_t)row * 2048;
          pr[colBase + c0]             = ua0;
          pr[colBase + 16 + c0]        = ua1;
          pr[1024 + colBase + c0]      = ub0;
          pr[1024 + colBase + 16 + c0] = ub1;
          const float ra[2] = {bf2f(ua0), bf2f(ua1)};
          const float rb[2] = {bf2f(ub0), bf2f(ub1)};
#pragma unroll
          for (int n = 0; n < 2; ++n) {
            if (dir == 0) { TB[n] = ra[n] * TB[n] + rb[n]; TA[n] = ra[n] * TA[n]; }
            else          { TB[n] = TA[n] * rb[n] + TB[n]; TA[n] = TA[n] * ra[n]; }
          }
        }
        // ordered butterfly across q — fragment rows are q-major contiguous
#pragma unroll
        for (int st = 0; st < 2; ++st) {
          const int msk = 16 << st;
          const bool self_later = (dir == 0) ? (((q >> st) & 1) != 0)
                                             : (((q >> st) & 1) == 0);
#pragma unroll
          for (int n = 0; n < 2; ++n) {
            float pA = __shfl_xor(TA[n], msk);
            float pB = __shfl_xor(TB[n], msk);
            if (self_later) { TB[n] = TA[n] * pB + TB[n]; TA[n] = TA[n] * pA; }
            else            { TB[n] = pA * TB[n] + pB;    TA[n] = pA * TA[n]; }
          }
        }
        CA[mm][0] = TA[0]; CA[mm][1] = TA[1];
        CB[mm][0] = TB[0]; CB[mm][1] = TB[1];
      }
      // combine fragment halves: mm=1 covers larger s (later for dir 0, earlier for dir 1)
      float FA[2], FB[2];
#pragma unroll
      for (int n = 0; n < 2; ++n) {
        if (dir == 0) { FA[n] = CA[1][n] * CA[0][n]; FB[n] = CA[1][n] * CB[0][n] + CB[1][n]; }
        else          { FA[n] = CA[0][n] * CA[1][n]; FB[n] = CA[0][n] * CB[1][n] + CB[0][n]; }
      }
      const int kk = waveM * 4 + k;
      const int c  = (dir == 0) ? (schunk0 + kk) : (63 - schunk0 - kk);
      if (q == 0) {
        size_t idx = (size_t)(batch * NCH + c) * Hn + colBase + c0;
        Acp[idx]      = FA[0]; Bcp[idx]      = FB[0];
        Acp[idx + 16] = FA[1]; Bcp[idx + 16] = FB[1];
      }
    }
  } else {
    const int colBase = bn * 256 + waveN * 64;
#pragma unroll
    for (int m = 0; m < MF; ++m) {
#pragma unroll
      for (int n = 0; n < 4; ++n) {
        int col = colBase + n * 16 + (lane & 15);
        float bv = (col < Nsplit) ? bias0[col] : bias1[col - Nsplit];
        if (outbf) {
#pragma unroll
          for (int r = 0; r < 4; ++r) {
            int row = rowBase + m * 16 + (lane >> 4) * 4 + r;
            outbf[(size_t)row * Ndim + col] = f2bf(acc[m][n][r] + bv);
          }
        } else {
#pragma unroll
          for (int r = 0; r < 4; ++r) {
            int row = rowBase + m * 16 + (lane >> 4) * 4 + r;
            out[(size_t)row * Ndim + col] = acc[m][n][r] + bv;
          }
        }
      }
    }
  }
}

// ---------------- scan pass 3 + prefix + LayerNorm ----------------
__global__ __launch_bounds__(1024) void scan_p3_ln(
    const unsigned short* __restrict__ pre,
    const float* __restrict__ Ac, const float* __restrict__ Bc,
    const unsigned short* __restrict__ resid,
    const float* __restrict__ gamma, const float* __restrict__ beta,
    unsigned short* __restrict__ out_bf,
    int bf_stride, int bf_off, int dir) {
  __shared__ unsigned short hsl[CHUNK][Hn];   // 64 KB
  const int h = threadIdx.x;
  const int c = blockIdx.x & (NCH - 1);
  const int b = blockIdx.x >> 6;              // NCH = 64

  // ---- prefix fold over chunks 0..c-1 ----
  float hprev = 0.0f;
  {
    int cc = 0;
    for (; cc + 8 <= c; cc += 8) {
      float Af[8], Bf[8];
#pragma unroll
      for (int qq = 0; qq < 8; ++qq) {
        size_t idx = (size_t)(b * NCH + cc + qq) * Hn + h;
        Af[qq] = Ac[idx];
        Bf[qq] = Bc[idx];
      }
#pragma unroll
      for (int qq = 0; qq < 8; ++qq) hprev = Af[qq] * hprev + Bf[qq];
    }
    for (; cc < c; ++cc) {
      size_t idx = (size_t)(b * NCH + cc) * Hn + h;
      hprev = Ac[idx] * hprev + Bc[idx];
    }
  }

  // ---- scan phase (no barriers; pure fold) ----
  for (int j = 0; j < CHUNK; ++j) {
    int t = c * CHUNK + j;
    int s = dir ? (Sn - 1 - t) : t;
    const unsigned short* p = pre + (size_t)(b * Sn + s) * 2048;
    float a  = bf2f(p[h]);
    float bv = bf2f(p[1024 + h]);
    hprev = a * hprev + bv;
    hsl[j][h] = f2bf(hprev);
  }
  __syncthreads();

  // ---- LN phase: wave wv handles rows 2wv, 2wv+1 ----
  const int lane = h & 63;
  const int wv   = h >> 6;
  float gm[16], bt[16];
  {
    const float4* gp = reinterpret_cast<const float4*>(gamma);
    const float4* bp = reinterpret_cast<const float4*>(beta);
#pragma unroll
    for (int half = 0; half < 2; ++half) {
      int base = half * 128 + lane * 2;
#pragma unroll
      for (int i = 0; i < 2; ++i) {
        float4 g4 = gp[base + i], b4 = bp[base + i];
        int o = half * 8 + i * 4;
        gm[o+0] = g4.x; gm[o+1] = g4.y; gm[o+2] = g4.z; gm[o+3] = g4.w;
        bt[o+0] = b4.x; bt[o+1] = b4.y; bt[o+2] = b4.z; bt[o+3] = b4.w;
      }
    }
  }

  for (int rr = 0; rr < 2; ++rr) {
    const int j = wv * 2 + rr;
    const int t = c * CHUNK + j;
    const int s = dir ? (Sn - 1 - t) : t;
    const size_t row = (size_t)(b * Sn + s);

    const uint4* rp = reinterpret_cast<const uint4*>(&hsl[j][0]);
    uint4 q0 = rp[lane], q1 = rp[64 + lane];
    uint32_t uw[8] = {q0.x, q0.y, q0.z, q0.w, q1.x, q1.y, q1.z, q1.w};
    float v[16];
#pragma unroll
    for (int k = 0; k < 8; ++k) {
      v[2*k]   = bf2f((unsigned short)(uw[k] & 0xffffu));
      v[2*k+1] = bf2f((unsigned short)(uw[k] >> 16));
    }
    if (resid) {
      const uint4* rf = reinterpret_cast<const uint4*>(resid + row * Hn);
      uint4 r0v = rf[lane], r1v = rf[64 + lane];
      uint32_t rw[8] = {r0v.x, r0v.y, r0v.z, r0v.w, r1v.x, r1v.y, r1v.z, r1v.w};
#pragma unroll
      for (int k = 0; k < 8; ++k) {
        v[2*k]   += bf2f((unsigned short)(rw[k] & 0xffffu));
        v[2*k+1] += bf2f((unsigned short)(rw[k] >> 16));
      }
    }
    float s1 = 0.0f, s2 = 0.0f;
#pragma unroll
    for (int m = 0; m < 16; ++m) { s1 += v[m]; s2 += v[m] * v[m]; }
#pragma unroll
    for (int off = 1; off < 64; off <<= 1) {
      s1 += __shfl_xor(s1, off);
      s2 += __shfl_xor(s2, off);
    }
    float mu  = s1 * (1.0f / Hn);
    float var = s2 * (1.0f / Hn) - mu * mu;
    float rs  = rsqrtf(var + 1e-5f);

    float o[16];
#pragma unroll
    for (int m = 0; m < 16; ++m) o[m] = (v[m] - mu) * rs * gm[m] + bt[m];

    uint4* ob = reinterpret_cast<uint4*>(out_bf + row * bf_stride + bf_off);
    uint4 w0, w1;
    w0.x = f2bf(o[0])  | ((u32)f2bf(o[1])  << 16);
    w0.y = f2bf(o[2])  | ((u32)f2bf(o[3])  << 16);
    w0.z = f2bf(o[4])  | ((u32)f2bf(o[5])  << 16);
    w0.w = f2bf(o[6])  | ((u32)f2bf(o[7])  << 16);
    w1.x = f2bf(o[8])  | ((u32)f2bf(o[9])  << 16);
    w1.y = f2bf(o[10]) | ((u32)f2bf(o[11]) << 16);
    w1.z = f2bf(o[12]) | ((u32)f2bf(o[13]) << 16);
    w1.w = f2bf(o[14]) | ((u32)f2bf(o[15]) << 16);
    ob[lane]      = w0;
    ob[64 + lane] = w1;
  }
}

// ---------------- launcher ----------------
extern "C" void kernel_launch(void* const* d_in, const int* in_sizes, int n_in,
                              void* d_out, int out_size, void* d_ws, size_t ws_size,
                              hipStream_t stream) {
  const float* x        = (const float*)d_in[0];
  const float* fwd_Wz   = (const float*)d_in[1];
  const float* fwd_bz   = (const float*)d_in[2];
  const float* fwd_Wh   = (const float*)d_in[3];
  const float* fwd_bh   = (const float*)d_in[4];
  const float* bwd_Wz   = (const float*)d_in[5];
  const float* bwd_bz   = (const float*)d_in[6];
  const float* bwd_Wh   = (const float*)d_in[7];
  const float* bwd_bh   = (const float*)d_in[8];
  const float* fusion_W = (const float*)d_in[9];
  const float* fusion_b = (const float*)d_in[10];
  const float* gamma    = (const float*)d_in[11];
  const float* beta     = (const float*)d_in[12];
  float* out = (float*)d_out;

  // workspace layout (pre holds (a,bv) bf16; actf/hs/pref slots unused)
  unsigned short* WzA    = (unsigned short*)d_ws;              // 2*4*1024*1024
  unsigned short* WhA    = WzA + 8ULL * 1024 * 1024;           // 2*4*1024*1024
  unsigned short* fusWbf = WhA + 8ULL * 1024 * 1024;           // 1024*2048
  unsigned short* xbf    = fusWbf + 2ULL * 1024 * 1024;        // 8192*1024
  unsigned short* actbf  = xbf + 8ULL * 1024 * 1024;           // 8192*1024 (GEMM in + resid)
  unsigned short* combbf = actbf + 8ULL * 1024 * 1024;         // 8192*2048
  float* actf = (float*)(combbf + 16ULL * 1024 * 1024);        // unused (layout keep)
  float* pre  = actf + 8ULL * 1024 * 1024;                     // 8192*2048 (bf16 uses half)
  float* hs   = pre + 16ULL * 1024 * 1024;                     // unused (layout keep)
  float* Ac   = hs + 8ULL * 1024 * 1024;                       // 4*NCH*1024
  float* Bc   = Ac + (size_t)Bn * NCH * Hn;
  float* pref = Bc + (size_t)Bn * NCH * Hn;                    // unused (layout keep)
  size_t need = (size_t)((char*)(pref + (size_t)Bn * NCH * Hn) - (char*)d_ws);
  if (ws_size < need) return;
  unsigned short* prebf = (unsigned short*)pre;

  // one fused cast dispatch
  cast_all<<<26624, 256, 0, stream>>>(
      fwd_Wz, bwd_Wz, fwd_Wh, bwd_Wh, fusion_W, x,
      WzA, WzA + 4ULL * 1024 * 1024, WhA, WhA + 4ULL * 1024 * 1024, fusWbf, xbf);

  for (int d = 0; d < 2; ++d) {
    const float* bz = d ? bwd_bz : fwd_bz;
    const float* bh = d ? bwd_bh : fwd_bh;
    for (int l = 0; l < Ln; ++l) {
      const unsigned short* a_in = (l == 0) ? xbf : actbf;
      const unsigned short* Wlo = WzA + (size_t)(d * 4 + l) * 1024 * 1024;
      const unsigned short* Whi = WhA + (size_t)(d * 4 + l) * 1024 * 1024;
      gemm_t<8, true><<<dim3(Mn / 256, 8), 512, 0, stream>>>(
          a_in, Wlo, Whi, bz + l * 1024, bh + l * 1024, 1024,
          nullptr, prebf, Ac, Bc, d, 2048, 1024);
      if (l < Ln - 1)
        scan_p3_ln<<<Bn * NCH, 1024, 0, stream>>>(
            prebf, Ac, Bc, (l == 0) ? nullptr : actbf, gamma, beta,
            actbf, 1024, 0, d);
      else
        scan_p3_ln<<<Bn * NCH, 1024, 0, stream>>>(
            prebf, Ac, Bc, actbf, gamma, beta,
            combbf, 2048, d * 1024, d);
    }
  }
  // fusion: out = comb(bf16) @ fusion_W^T + fusion_b (f32 output)
  gemm_t<4, false><<<dim3(Mn / 128, 1024 / 256), 512, 0, stream>>>(
      combbf, fusWbf, fusWbf, fusion_b, fusion_b, 1 << 30, out, nullptr,
      nullptr, nullptr, 0, 1024, 2048);
}